// Round 2
// baseline (10815.333 us; speedup 1.0000x reference)
//
#include <hip/hip_runtime.h>

// ---------------------------------------------------------------------------
// TT circuit expectation <psi|U^dag O U|psi>, NQ=8 sites, r=64 d=16 rl=16 ro=4.
// ws budget is exactly 256 MiB -> chunk the bra-state bond A (64) into 4
// chunks of 16. A is a pure batch dim (introduced at step 1, never
// contracted), so each chunk runs the whole 5-GEMM chain on 1/4-size
// intermediates (16.78M floats) and writes a disjoint env'[A-slice].
//
// Per (site, chunk), 5 TN-GEMMs  C = A^T[KxM] * B[KxN], permuted stores so
// the next GEMM's contraction indices are K-major and a4 (A within chunk)
// stays innermost (float4 stores).
//
// Layouts (flat fp32 indices; a4 = A - A0, chunk width 16):
//  env  [a][l][o][m][b]        a*65536 + l*4096 + o*1024 + m*64 + b
//  t1   [(l,i)][o][m][b][a4]   (l*16+i)*65536 + o*16384 + m*1024 + b*16 + a4
//  t2   [(o,j)][L][m][b][a4]   (o*16+j)*262144 + L*16384 + m*1024 + b*16 + a4
//  t3   [(m,k)][O][b][L][a4]   (m*16+k)*65536 + O*16384 + b*256 + L*16 + a4
//  t4   [(b,s)][M][L][O][a4]   (b*16+s)*16384 + M*1024 + L*64 + O*16 + a4
//  env' [A][L][O][M][B]        (A0+a4)*65536 + L*4096 + O*1024 + M*64 + B
// ---------------------------------------------------------------------------

static constexpr int BIGC = 16777216;   // floats per big chunk buffer (67 MB)
static constexpr int ENVC = 4194304;    // floats per env buffer (16.8 MB)
static constexpr int UDC  = 524288;     // floats, 8 sites x 256x256 Ud-pack

__global__ void write_diag_kernel(float* out, float v) {
    if (threadIdx.x == 0 && blockIdx.x == 0) out[0] = v;
}

__global__ void init_env0(float* __restrict__ env) {
    int i = blockIdx.x * 256 + threadIdx.x;
    env[i] = (i == 0) ? 1.0f : 0.0f;
}

// ud[q][(l*16+i)][(j*16+L)] = layer[q][l][j][i][L]   (tt_dagger transpose)
__global__ void prep_udmat(const float* __restrict__ layer, float* __restrict__ ud) {
    int idx = blockIdx.x * 256 + threadIdx.x;   // 8*65536 total
    int q  = idx >> 16;
    int r  = idx & 65535;
    int li = r >> 8;     // l*16+i
    int jL = r & 255;    // j*16+L
    int l = li >> 4, i = li & 15, j = jL >> 4, L = jL & 15;
    ud[idx] = layer[((size_t)q << 16) + (size_t)(((l * 16 + j) * 16 + i) * 16 + L)];
}

__global__ void copy_out(const float* __restrict__ env, float* __restrict__ out) {
    out[0] = env[0];
}

// Permuted store address; m = output row (small dim), n = output col (big dim)
template <int SM>
__device__ __forceinline__ int store_addr(int m, int n, int A0) {
    if constexpr (SM == 1) {
        // m=(l,o,m2,b) [env cols], n=(i,a4)  -> t1
        return ((m >> 12) * 16 + (n >> 4)) * 65536 + (m & 4095) * 16 + (n & 15);
    } else if constexpr (SM == 2) {
        // m=(j,L), n=(o,m2,b,a4)  -> t2
        return ((n >> 14) * 16 + (m >> 4)) * 262144 + (m & 15) * 16384 + (n & 16383);
    } else if constexpr (SM == 3) {
        // m=(k,O2), n=(L,m2,b,a4)  -> t3
        return (((n >> 10) & 15) * 16 + (m >> 2)) * 65536 + (m & 3) * 16384 +
               ((n >> 4) & 63) * 256 + (n >> 14) * 16 + (n & 15);
    } else if constexpr (SM == 4) {
        // m=(s,M2), n=(O2,b,L,a4)  -> t4
        return (((n >> 8) & 63) * 16 + (m >> 4)) * 16384 + (m & 15) * 1024 +
               ((n >> 4) & 15) * 64 + (n >> 14) * 16 + (n & 15);
    } else {
        // m=B, n=(M2,L,O2,a4)  -> env' slice at A0
        return (A0 + (n & 15)) * 65536 + ((n >> 6) & 15) * 4096 +
               ((n >> 4) & 3) * 1024 + (n >> 10) * 64 + m;
    }
}

// BL=0: B is K-major contiguous (row stride N). BL=1: B = S[a][i][A] sliced,
// col n=(i,a4): addr = k*1024 + (n>>4)*64 + A0 + (n&15).
template <int BM, int BN, int BK, int TM, int TN, int SM, int BL>
__global__ __launch_bounds__(256) void gemm_tn(const float* __restrict__ A,
                                               const float* __restrict__ B,
                                               float* __restrict__ C,
                                               int M, int N, int K, int A0) {
    constexpr int TNB = BN / TN;
    constexpr int TMB = BM / TM;
    static_assert(TNB * TMB == 256, "block must be 256 threads");
    __shared__ float As[BK * BM];
    __shared__ float Bs[BK * BN];

    const int tid = threadIdx.x;
    const int tx  = tid % TNB;
    const int ty  = tid / TNB;
    const int n0  = blockIdx.x * BN;
    const int m0  = blockIdx.y * BM;

    float acc[TM][TN];
#pragma unroll
    for (int i = 0; i < TM; i++)
#pragma unroll
        for (int j = 0; j < TN; j++) acc[i][j] = 0.0f;

    for (int k0 = 0; k0 < K; k0 += BK) {
        constexpr int AV = (BK * BM) / (256 * 4);
#pragma unroll
        for (int v = 0; v < AV; v++) {
            int e = (tid + v * 256) * 4;
            int kk = e / BM, mm = e % BM;
            *(float4*)(As + kk * BM + mm) =
                *(const float4*)(A + (size_t)(k0 + kk) * M + (m0 + mm));
        }
        constexpr int BV = (BK * BN) / (256 * 4);
#pragma unroll
        for (int v = 0; v < BV; v++) {
            int e = (tid + v * 256) * 4;
            int kk = e / BN, nn = e % BN;
            const float* src;
            if constexpr (BL == 0) {
                src = B + (size_t)(k0 + kk) * N + (n0 + nn);
            } else {
                int gn = n0 + nn;
                src = B + (size_t)(k0 + kk) * 1024 + (gn >> 4) * 64 + A0 + (gn & 15);
            }
            *(float4*)(Bs + kk * BN + nn) = *(const float4*)src;
        }
        __syncthreads();
#pragma unroll
        for (int k = 0; k < BK; k++) {
            float a[TM], b[TN];
#pragma unroll
            for (int i = 0; i < TM; i += 4)
                *(float4*)(a + i) = *(float4*)(As + k * BM + ty * TM + i);
#pragma unroll
            for (int j = 0; j < TN; j += 4)
                *(float4*)(b + j) = *(float4*)(Bs + k * BN + tx * TN + j);
#pragma unroll
            for (int i = 0; i < TM; i++)
#pragma unroll
                for (int j = 0; j < TN; j++) acc[i][j] += a[i] * b[j];
        }
        __syncthreads();
    }

#pragma unroll
    for (int i = 0; i < TM; i++) {
        int m = m0 + ty * TM + i;
        if constexpr (SM == 5) {
            // scattered scalar stores into env' slice (small tensor)
#pragma unroll
            for (int j = 0; j < TN; j++) {
                int n = n0 + tx * TN + j;
                C[store_addr<SM>(m, n, A0)] = acc[i][j];
            }
        } else {
            // a4 (n&15) is innermost of the destination: groups of 4 contiguous
#pragma unroll
            for (int jg = 0; jg < TN; jg += 4) {
                int n = n0 + tx * TN + jg;
                float4 v = make_float4(acc[i][jg], acc[i][jg + 1],
                                       acc[i][jg + 2], acc[i][jg + 3]);
                *(float4*)(C + store_addr<SM>(m, n, A0)) = v;
            }
        }
    }
}

extern "C" void kernel_launch(void* const* d_in, const int* in_sizes, int n_in,
                              void* d_out, int out_size, void* d_ws, size_t ws_size,
                              hipStream_t stream) {
    const float* state = (const float*)d_in[0];   // [8,64,16,64]
    const float* layer = (const float*)d_in[1];   // [1,8,16,16,16,16]
    const float* oper  = (const float*)d_in[2];   // [8,4,16,16,4]
    float* out = (float*)d_out;

    const size_t need = ((size_t)2 * BIGC + 2 * ENVC + UDC) * 4ull;  // ~170 MB
    if (ws_size < need) {
        write_diag_kernel<<<1, 64, 0, stream>>>(out, (float)ws_size);
        return;
    }

    float* big0 = (float*)d_ws;
    float* big1 = big0 + BIGC;
    float* envA = big1 + BIGC;
    float* envB = envA + ENVC;
    float* ud   = envB + ENVC;

    prep_udmat<<<2048, 256, 0, stream>>>(layer, ud);
    init_env0<<<ENVC / 256, 256, 0, stream>>>(envA);

    for (int q = 0; q < 8; q++) {
        float* ein  = (q & 1) ? envB : envA;
        float* eout = (q & 1) ? envA : envB;
        const float* Sq = state + (size_t)q * 65536;
        const float* Uq = layer + (size_t)q * 65536;
        const float* Oq = oper  + (size_t)q * 4096;
        const float* Dq = ud    + (size_t)q * 65536;

        for (int c = 0; c < 4; c++) {
            int A0 = c * 16;
            // G1: t1[(l,i);(o,m,b,a4)] = sum_a env[a;(l,o,m,b)] * S[a;(i,A0+a4)]
            gemm_tn<128, 128, 16, 8, 8, 1, 1><<<dim3(2, 512), 256, 0, stream>>>(
                ein, Sq, big0, 65536, 256, 64, A0);
            // G2: t2[(o,j),L;(m,b,a4)] = sum_{l,i} Ud[(l,i);(j,L)] * t1
            gemm_tn<128, 128, 16, 8, 8, 2, 0><<<dim3(512, 2), 256, 0, stream>>>(
                Dq, big0, big1, 256, 65536, 256, 0);
            // G3: t3[(m,k);O,b,L,a4] = sum_{o,j} Oq[(o,j);(k,O)] * t2
            gemm_tn<64, 128, 16, 4, 8, 3, 0><<<dim3(2048, 1), 256, 0, stream>>>(
                Oq, big1, big0, 64, 262144, 64, 0);
            // G4: t4[(b,s);M,L,O,a4] = sum_{m,k} Uq[(m,k);(s,M)] * t3
            gemm_tn<128, 128, 16, 8, 8, 4, 0><<<dim3(512, 2), 256, 0, stream>>>(
                Uq, big0, big1, 256, 65536, 256, 0);
            // G5: env'[A0+a4,L,O,M,B] = sum_{b,s} S[(b,s);B] * t4
            gemm_tn<64, 64, 16, 4, 4, 5, 0><<<dim3(256, 1), 256, 0, stream>>>(
                Sq, big1, eout, 64, 16384, 1024, A0);
        }
    }
    // after q=7 (odd) the result env lives in envA
    copy_out<<<1, 1, 0, stream>>>(envA, out);
}

// Round 3
// 5940.274 us; speedup vs baseline: 1.8207x; 1.8207x over previous
//
#include <hip/hip_runtime.h>

// ---------------------------------------------------------------------------
// <psi|U^dag O U|psi>, NQ=8, r=64 d=16 rl=16 ro=4.
// R3: (a) boundary sites 0 and 7 via cheap rank-structured chains (fp32 exact);
//     (b) middle sites 1..6: G2/G4 (the K=256 GEMMs, 73% of MACs) on bf16x3
//         MFMA (hi/lo split, Ah*Bh + Ah*Bl + Al*Bh, fp32 accumulate).
// Data flow per (site q=1..6, A-chunk c=0..3):
//   G1 (fp32 vec)  env x S      -> P  (uint plane: bf16 hi|lo<<16, [k/32][n][k%32])
//   G2 (MFMA)      Ud-pack x P  -> F  (fp32 t2)
//   G3 (fp32 vec)  O x F        -> P  (uint plane, t3)
//   G4 (MFMA)      U-pack  x P  -> F  (fp32 t4)
//   G5 (fp32 vec)  S x F        -> env'
// A-operands for MFMA are pre-packed per-site in exact A-fragment order
// (lane = m mod 16, 8 consecutive k per lane) and read straight from global/L2.
// ---------------------------------------------------------------------------

typedef __attribute__((ext_vector_type(8))) short bf16x8;
typedef __attribute__((ext_vector_type(4))) float f32x4;
typedef __attribute__((ext_vector_type(4))) unsigned short us4;

static __device__ __forceinline__ unsigned short f2bf(float x) {
    union { float f; unsigned u; } a; a.f = x;
    return (unsigned short)((a.u + 0x7FFF + ((a.u >> 16) & 1)) >> 16);
}
static __device__ __forceinline__ float bf2f(unsigned short h) {
    union { unsigned u; float f; } a; a.u = (unsigned)h << 16; return a.f;
}
static __device__ __forceinline__ unsigned split2(float x) {
    unsigned short h = f2bf(x);
    unsigned short l = f2bf(x - bf2f(h));
    return (unsigned)h | ((unsigned)l << 16);
}

__global__ void write_diag_kernel(float* out, float v) {
    if (threadIdx.x == 0 && blockIdx.x == 0) out[0] = v;
}
__global__ void zero_out(float* o) {
    if (threadIdx.x == 0 && blockIdx.x == 0) o[0] = 0.0f;
}

// ---- A-operand fragment packs for G2 (Ud) and G4 (U) --------------------
// Layout: [(q*8+k0)*16+mt][hl][lane][8 shorts]; frag = Amat[k0*32+quad*8+j][mt*16+(lane&15)]
__global__ void prep_apack(const float* __restrict__ layer,
                           unsigned short* __restrict__ Ap2,
                           unsigned short* __restrict__ Ap4) {
    int idx = blockIdx.x * 256 + threadIdx.x;   // 65536
    int q = idx >> 13, k0 = (idx >> 10) & 7, mt = (idx >> 6) & 15, lane = idx & 63;
    int quad = lane >> 4, r = lane & 15;
    unsigned short h2[8], l2[8], h4[8], l4[8];
#pragma unroll
    for (int j = 0; j < 8; j++) {
        int k = k0 * 32 + quad * 8 + j;   // 0..255
        int m = mt * 16 + r;              // 0..255
        // G2: Amat[k=(l,i)][m=(j2,L)] = layer[q][l][j2][i][L]
        float v2 = layer[(size_t)q * 65536 +
                         (size_t)((((k >> 4) * 16 + (m >> 4)) * 16 + (k & 15)) * 16 + (m & 15))];
        // G4: Amat[k=(m2,k2)][m=(s,M)] = layer[q][m2][k2][s][M]
        float v4 = layer[(size_t)q * 65536 +
                         (size_t)((((k >> 4) * 16 + (k & 15)) * 16 + (m >> 4)) * 16 + (m & 15))];
        unsigned short hh = f2bf(v2); h2[j] = hh; l2[j] = f2bf(v2 - bf2f(hh));
        hh = f2bf(v4); h4[j] = hh; l4[j] = f2bf(v4 - bf2f(hh));
    }
    size_t base = ((size_t)((q * 8 + k0) * 16 + mt) * 2) * 512 + lane * 8;
    *(us4*)(Ap2 + base)       = *(us4*)&h2[0];
    *(us4*)(Ap2 + base + 4)   = *(us4*)&h2[4];
    *(us4*)(Ap2 + base + 512) = *(us4*)&l2[0];
    *(us4*)(Ap2 + base + 516) = *(us4*)&l2[4];
    *(us4*)(Ap4 + base)       = *(us4*)&h4[0];
    *(us4*)(Ap4 + base + 4)   = *(us4*)&h4[4];
    *(us4*)(Ap4 + base + 512) = *(us4*)&l4[0];
    *(us4*)(Ap4 + base + 516) = *(us4*)&l4[4];
}

// ---- site 0 (env0 = delta): env1[A,L,O,M,B] built by a cheap chain ------
__global__ void s0_g2(const float* __restrict__ state, const float* __restrict__ layer,
                      float* __restrict__ g2) {
    int t = blockIdx.x * 256 + threadIdx.x;          // 16384: [A][j][L]
    int A = t >> 8, j = (t >> 4) & 15, L = t & 15;
    float s = 0;
    for (int i = 0; i < 16; i++) s += state[i * 64 + A] * layer[(j * 16 + i) * 16 + L];
    g2[t] = s;
}
__global__ void s0_g3(const float* __restrict__ g2, const float* __restrict__ oper,
                      float* __restrict__ g3) {
    int t = blockIdx.x * 256 + threadIdx.x;          // 65536: [A][L][k][O]
    int A = t >> 10, L = (t >> 6) & 15, k = (t >> 2) & 15, O = t & 3;
    float s = 0;
    for (int j = 0; j < 16; j++) s += g2[A * 256 + j * 16 + L] * oper[(j * 16 + k) * 4 + O];
    g3[t] = s;
}
__global__ void s0_g4(const float* __restrict__ g3, const float* __restrict__ layer,
                      float* __restrict__ g4) {
    int t = blockIdx.x * 256 + threadIdx.x;          // 1048576: [A][L][O][s][M]
    int A = t >> 14, L = (t >> 10) & 15, O = (t >> 8) & 3, sp = (t >> 4) & 15, M = t & 15;
    float s = 0;
    for (int k = 0; k < 16; k++)
        s += g3[A * 1024 + L * 64 + k * 4 + O] * layer[(k * 16 + sp) * 16 + M];
    g4[t] = s;
}
__global__ void s0_env(const float* __restrict__ g4, const float* __restrict__ state,
                       float* __restrict__ env) {
    int t = blockIdx.x * 256 + threadIdx.x;          // 4194304: [A][L][O][M][B]
    int A = t >> 16, L = (t >> 12) & 15, O = (t >> 10) & 3, M = (t >> 6) & 15, B = t & 63;
    float s = 0;
    for (int sp = 0; sp < 16; sp++)
        s += g4[A * 16384 + L * 1024 + O * 256 + sp * 16 + M] * state[sp * 64 + B];
    env[t] = s;
}

// ---- site 7: out = <env7, w>, w built by a cheap chain ------------------
__global__ void s7_c1(const float* __restrict__ state, const float* __restrict__ layer,
                      float* __restrict__ c1) {
    int t = blockIdx.x * 256 + threadIdx.x;          // 16384: [l][a][j]
    int l = t >> 10, a = (t >> 4) & 63, j = t & 15;
    float s = 0;
    for (int i = 0; i < 16; i++)
        s += state[7 * 65536 + (a * 16 + i) * 64] * layer[7 * 65536 + ((l * 16 + j) * 16 + i) * 16];
    c1[t] = s;
}
__global__ void s7_c2(const float* __restrict__ c1, const float* __restrict__ oper,
                      float* __restrict__ c2) {
    int t = blockIdx.x * 256 + threadIdx.x;          // 65536: [o][l][a][k]
    int o = t >> 14, l = (t >> 10) & 15, a = (t >> 4) & 63, k = t & 15;
    float s = 0;
    for (int j = 0; j < 16; j++)
        s += c1[l * 1024 + a * 16 + j] * oper[7 * 4096 + ((o * 16 + j) * 16 + k) * 4];
    c2[t] = s;
}
__global__ void s7_c3(const float* __restrict__ c2, const float* __restrict__ layer,
                      float* __restrict__ c3) {
    int t = blockIdx.x * 256 + threadIdx.x;          // 1048576: [m][o][l][a][s]
    int m = t >> 16, o = (t >> 14) & 3, l = (t >> 10) & 15, a = (t >> 4) & 63, sp = t & 15;
    float s = 0;
    for (int k = 0; k < 16; k++)
        s += c2[o * 16384 + l * 1024 + a * 16 + k] *
             layer[7 * 65536 + ((m * 16 + k) * 16 + sp) * 16];
    c3[t] = s;
}
__global__ void s7_w(const float* __restrict__ c3, const float* __restrict__ state,
                     float* __restrict__ w) {
    int t = blockIdx.x * 256 + threadIdx.x;          // 4194304: [a][l][o][m][b]
    int a = t >> 16, l = (t >> 12) & 15, o = (t >> 10) & 3, m = (t >> 6) & 15, b = t & 63;
    float s = 0;
    for (int sp = 0; sp < 16; sp++)
        s += c3[m * 65536 + o * 16384 + l * 1024 + a * 16 + sp] *
             state[7 * 65536 + (b * 16 + sp) * 64];
    w[t] = s;
}
__global__ void s7_dot(const float* __restrict__ env, const float* __restrict__ w,
                       float* __restrict__ out) {
    __shared__ float red[256];
    int t = threadIdx.x;
    size_t base = (size_t)blockIdx.x * 4096 + (size_t)t * 16;
    float s = 0;
    for (int e = 0; e < 16; e++) s += env[base + e] * w[base + e];
    red[t] = s; __syncthreads();
    for (int off = 128; off; off >>= 1) { if (t < off) red[t] += red[t + off]; __syncthreads(); }
    if (t == 0) atomicAdd(out, red[0]);
}

// ---- fp32 vector GEMM (G1 / G3 / G5), C = A^T[KxM] * B[KxN] --------------
// SM=1: -> uint plane (t1), SM=3: -> uint plane (t3), SM=5: -> env' fp32
template <int BM, int BN, int BK, int TM, int TN, int SM, int BL>
__global__ __launch_bounds__(256) void gemm_tn(const float* __restrict__ A,
                                               const float* __restrict__ B,
                                               float* __restrict__ Cf,
                                               unsigned* __restrict__ Cu,
                                               int M, int N, int K, int A0) {
    constexpr int TNB = BN / TN;
    constexpr int TMB = BM / TM;
    static_assert(TNB * TMB == 256, "block must be 256 threads");
    __shared__ float As[BK * BM];
    __shared__ float Bs[BK * BN];

    const int tid = threadIdx.x;
    const int tx = tid % TNB, ty = tid / TNB;
    const int n0 = blockIdx.x * BN, m0 = blockIdx.y * BM;

    float acc[TM][TN];
#pragma unroll
    for (int i = 0; i < TM; i++)
#pragma unroll
        for (int j = 0; j < TN; j++) acc[i][j] = 0.0f;

    for (int k0 = 0; k0 < K; k0 += BK) {
        constexpr int AV = (BK * BM) / (256 * 4);
#pragma unroll
        for (int v = 0; v < AV; v++) {
            int e = (tid + v * 256) * 4;
            int kk = e / BM, mm = e % BM;
            *(float4*)(As + kk * BM + mm) =
                *(const float4*)(A + (size_t)(k0 + kk) * M + (m0 + mm));
        }
        constexpr int BV = (BK * BN) / (256 * 4);
#pragma unroll
        for (int v = 0; v < BV; v++) {
            int e = (tid + v * 256) * 4;
            int kk = e / BN, nn = e % BN;
            const float* src;
            if constexpr (BL == 0) {
                src = B + (size_t)(k0 + kk) * N + (n0 + nn);
            } else {
                int gn = n0 + nn;
                src = B + (size_t)(k0 + kk) * 1024 + (gn >> 4) * 64 + A0 + (gn & 15);
            }
            *(float4*)(Bs + kk * BN + nn) = *(const float4*)src;
        }
        __syncthreads();
#pragma unroll
        for (int k = 0; k < BK; k++) {
            float a[TM], b[TN];
#pragma unroll
            for (int i = 0; i < TM; i += 4)
                *(float4*)(a + i) = *(float4*)(As + k * BM + ty * TM + i);
#pragma unroll
            for (int j = 0; j < TN; j += 4)
                *(float4*)(b + j) = *(float4*)(Bs + k * BN + tx * TN + j);
#pragma unroll
            for (int i = 0; i < TM; i++)
#pragma unroll
                for (int j = 0; j < TN; j++) acc[i][j] += a[i] * b[j];
        }
        __syncthreads();
    }

#pragma unroll
    for (int i = 0; i < TM; i++) {
        int m = m0 + ty * TM + i;
#pragma unroll
        for (int j = 0; j < TN; j++) {
            int n = n0 + tx * TN + j;
            if constexpr (SM == 1) {
                // m=(l,o,m2,b), n=(i2,a4) -> t1 plane, k=(l,i2), nn=(o,m2,b,a4)
                int kn = ((m >> 12) << 4) + (n >> 4);
                int nn = (m & 4095) * 16 + (n & 15);
                Cu[(size_t)(kn >> 5) * 2097152 + (size_t)nn * 32 + (kn & 31)] =
                    split2(acc[i][j]);
            } else if constexpr (SM == 3) {
                // m=(k,O2), n=(L,m2,b,a4) -> t3 plane, k=(m2,k), nn=(O2,b,L,a4)
                int kn = (((n >> 10) & 15) << 4) + (m >> 2);
                int nn = (m & 3) * 16384 + ((n >> 4) & 63) * 256 + ((n >> 14) << 4) + (n & 15);
                Cu[(size_t)(kn >> 5) * 2097152 + (size_t)nn * 32 + (kn & 31)] =
                    split2(acc[i][j]);
            } else {
                // m=B, n=(M2,L,O2,a4) -> env'[A0+a4][L][O][M][B]
                Cf[(size_t)(A0 + (n & 15)) * 65536 + ((n >> 6) & 15) * 4096 +
                   ((n >> 4) & 3) * 1024 + (n >> 10) * 64 + m] = acc[i][j];
            }
        }
    }
}

// ---- bf16x3 MFMA GEMM for G2/G4: M=256,N=65536,K=256 ---------------------
// C[m,n] = sum_k Amat[k,m]*B[k,n]; B from uint plane [k/32][n][k%32] (h|l<<16);
// A from fragment-packed global. 16x16x32 MFMA; block 128x128, 4 waves 64x64.
template <int SM>
__global__ __launch_bounds__(256) void gemm_mfma(const unsigned* __restrict__ Bp,
                                                 const unsigned short* __restrict__ Ap,
                                                 float* __restrict__ C) {
    __shared__ unsigned short Bs_h[4096];   // [n'(128)][kk(32)]
    __shared__ unsigned short Bs_l[4096];
    const int tid = threadIdx.x;
    const int lane = tid & 63, wave = tid >> 6;
    const int wm = wave >> 1, wn = wave & 1;
    const int quad = lane >> 4, lr = lane & 15;
    const int n0 = blockIdx.x * 128;
    const int nrow = tid >> 1, half = tid & 1;

    f32x4 acc[4][4];
#pragma unroll
    for (int i = 0; i < 4; i++)
#pragma unroll
        for (int j = 0; j < 4; j++)
#pragma unroll
            for (int r = 0; r < 4; r++) acc[i][j][r] = 0.0f;

    for (int k0 = 0; k0 < 8; k0++) {
        // stage B tile: contiguous 16KB (h/l unpack) into LDS
        const unsigned* src = Bp + (size_t)k0 * 2097152 + (size_t)(n0 + nrow) * 32 + half * 16;
        uint4 u[4];
#pragma unroll
        for (int g = 0; g < 4; g++) u[g] = ((const uint4*)src)[g];
        int lb = nrow * 32 + half * 16;
#pragma unroll
        for (int g = 0; g < 4; g++) {
            us4 hv, lv;
            hv[0] = (unsigned short)u[g].x; lv[0] = (unsigned short)(u[g].x >> 16);
            hv[1] = (unsigned short)u[g].y; lv[1] = (unsigned short)(u[g].y >> 16);
            hv[2] = (unsigned short)u[g].z; lv[2] = (unsigned short)(u[g].z >> 16);
            hv[3] = (unsigned short)u[g].w; lv[3] = (unsigned short)(u[g].w >> 16);
            *(us4*)(&Bs_h[lb + g * 4]) = hv;
            *(us4*)(&Bs_l[lb + g * 4]) = lv;
        }
        __syncthreads();

        bf16x8 ah[4], al[4];
#pragma unroll
        for (int mt = 0; mt < 4; mt++) {
            int gmt = blockIdx.y * 8 + wm * 4 + mt;
            const unsigned short* ap = Ap + ((size_t)(k0 * 16 + gmt) * 2) * 512 + lane * 8;
            ah[mt] = *(const bf16x8*)ap;
            al[mt] = *(const bf16x8*)(ap + 512);
        }
#pragma unroll
        for (int nt = 0; nt < 4; nt++) {
            int nl = wn * 64 + nt * 16 + lr;
            bf16x8 bh = *(bf16x8*)(&Bs_h[nl * 32 + quad * 8]);
            bf16x8 bl = *(bf16x8*)(&Bs_l[nl * 32 + quad * 8]);
#pragma unroll
            for (int mt = 0; mt < 4; mt++) {
                acc[mt][nt] = __builtin_amdgcn_mfma_f32_16x16x32_bf16(ah[mt], bh, acc[mt][nt], 0, 0, 0);
                acc[mt][nt] = __builtin_amdgcn_mfma_f32_16x16x32_bf16(ah[mt], bl, acc[mt][nt], 0, 0, 0);
                acc[mt][nt] = __builtin_amdgcn_mfma_f32_16x16x32_bf16(al[mt], bh, acc[mt][nt], 0, 0, 0);
            }
        }
        __syncthreads();
    }

#pragma unroll
    for (int mt = 0; mt < 4; mt++)
#pragma unroll
        for (int nt = 0; nt < 4; nt++)
#pragma unroll
            for (int r = 0; r < 4; r++) {
                int m = (blockIdx.y * 8 + wm * 4 + mt) * 16 + quad * 4 + r;
                int n = n0 + wn * 64 + nt * 16 + lr;
                size_t addr;
                if constexpr (SM == 2)   // t2[(o,j)][L][m2,b,a4]
                    addr = (size_t)((n >> 14) * 16 + (m >> 4)) * 262144 +
                           (m & 15) * 16384 + (n & 16383);
                else                     // t4[(b,s)][M][L][O][a4]
                    addr = (size_t)(((n >> 8) & 63) * 16 + (m >> 4)) * 16384 +
                           (m & 15) * 1024 + ((n >> 4) & 15) * 64 + ((n >> 14) << 4) + (n & 15);
                C[addr] = acc[mt][nt][r];
            }
}

extern "C" void kernel_launch(void* const* d_in, const int* in_sizes, int n_in,
                              void* d_out, int out_size, void* d_ws, size_t ws_size,
                              hipStream_t stream) {
    const float* state = (const float*)d_in[0];   // [8,64,16,64]
    const float* layer = (const float*)d_in[1];   // [1,8,16,16,16,16]
    const float* oper  = (const float*)d_in[2];   // [8,4,16,16,4]
    float* out = (float*)d_out;

    // ws: F(16.8M f32) | P(16.8M u32) | envA | envB | Ap2 | Ap4
    const size_t need = (16777216ull + 16777216ull + 2 * 4194304ull) * 4ull + 2 * 2097152ull;
    if (ws_size < need) {
        write_diag_kernel<<<1, 64, 0, stream>>>(out, (float)ws_size);
        return;
    }
    float* F    = (float*)d_ws;
    unsigned* P = (unsigned*)(F + 16777216);
    float* envA = (float*)(P + 16777216);
    float* envB = envA + 4194304;
    unsigned short* Ap2 = (unsigned short*)(envB + 4194304);
    unsigned short* Ap4 = Ap2 + 1048576;

    prep_apack<<<256, 256, 0, stream>>>(layer, Ap2, Ap4);

    // site 0 -> envB (exact fp32)
    s0_g2<<<64, 256, 0, stream>>>(state, layer, F);
    s0_g3<<<256, 256, 0, stream>>>(F, oper, F + 16384);
    s0_g4<<<4096, 256, 0, stream>>>(F + 16384, layer, F + 81920);
    s0_env<<<16384, 256, 0, stream>>>(F + 81920, state, envB);

    for (int q = 1; q < 7; q++) {
        float* ein  = (q & 1) ? envB : envA;
        float* eout = (q & 1) ? envA : envB;
        const float* Sq = state + (size_t)q * 65536;
        const float* Oq = oper + (size_t)q * 4096;
        for (int c = 0; c < 4; c++) {
            int A0 = c * 16;
            gemm_tn<128, 128, 16, 8, 8, 1, 1><<<dim3(2, 512), 256, 0, stream>>>(
                ein, Sq, nullptr, P, 65536, 256, 64, A0);
            gemm_mfma<2><<<dim3(512, 2), 256, 0, stream>>>(P, Ap2 + (size_t)q * 131072, F);
            gemm_tn<64, 128, 16, 4, 8, 3, 0><<<dim3(2048, 1), 256, 0, stream>>>(
                Oq, F, nullptr, P, 64, 262144, 64, 0);
            gemm_mfma<4><<<dim3(512, 2), 256, 0, stream>>>(P, Ap4 + (size_t)q * 131072, F);
            gemm_tn<64, 64, 16, 4, 4, 5, 0><<<dim3(256, 1), 256, 0, stream>>>(
                Sq, F, eout, nullptr, 64, 16384, 1024, A0);
        }
    }

    // site 7: out = <env7 (in envB), w>
    s7_c1<<<64, 256, 0, stream>>>(state, layer, F);
    s7_c2<<<256, 256, 0, stream>>>(F, oper, F + 16384);
    s7_c3<<<4096, 256, 0, stream>>>(F + 16384, layer, F + 81920);
    s7_w<<<16384, 256, 0, stream>>>(F + 81920, state, F + 1130496);
    zero_out<<<1, 64, 0, stream>>>(out);
    s7_dot<<<1024, 256, 0, stream>>>(envB, F + 1130496, out);
}